// Round 1
// baseline (960.120 us; speedup 1.0000x reference)
//
#include <hip/hip_runtime.h>

// BilinearUpSampling3D: (2,96,96,48,32) f32 -> (2,192,192,96,32) f32.
// TF v1 align_corners=False with exactly 2x per axis => even out idx = copy,
// odd out idx = 0.5*(in[i] + in[min(i+1, n-1)]). Separable, weights exact.
//
// One thread = one float4 channel chunk of a 2x2x2 output voxel block:
// 8 float4 loads -> 8 float4 stores (1:1 in float4 units). Lane order
// (c4 fastest, then k) makes a wave's loads a contiguous 1KB and every
// store an aligned full 128B segment.

__device__ __forceinline__ float4 f4add(const float4 a, const float4 b) {
    return make_float4(a.x + b.x, a.y + b.y, a.z + b.z, a.w + b.w);
}
__device__ __forceinline__ float4 f4scale(const float4 a, const float s) {
    return make_float4(a.x * s, a.y * s, a.z * s, a.w * s);
}

// Input strides in float4 units: c4:1, k:8, j:384, i:36864, b:3538944
// Output strides in float4 units: c4:1, d:8, w:768, h:147456, b:28311552
__global__ __launch_bounds__(256) void upsample2x_kernel(
    const float4* __restrict__ in, float4* __restrict__ out) {
    const int tid = blockIdx.x * 256 + threadIdx.x;  // grid sized exactly
    const int c4 = tid & 7;
    int t = tid >> 3;
    const int k = t % 48; t /= 48;
    const int j = t % 96; t /= 96;
    const int i = t % 96;
    const int b = t / 96;

    // clamped neighbor offsets (0 at the edge -> reload same element)
    const int dk = (k < 47) ? 8 : 0;
    const int dj = (j < 95) ? 384 : 0;
    const int di = (i < 95) ? 36864 : 0;

    const float4* p = in + (size_t)b * 3538944 + i * 36864 + j * 384 + k * 8 + c4;
    const float4 c000 = p[0];
    const float4 c001 = p[dk];
    const float4 c010 = p[dj];
    const float4 c011 = p[dj + dk];
    const float4 c100 = p[di];
    const float4 c101 = p[di + dk];
    const float4 c110 = p[di + dj];
    const float4 c111 = p[di + dj + dk];

    const float4 s00 = f4add(c000, c001);  // h0 w0, d-pair sum
    const float4 s01 = f4add(c010, c011);  // h0 w1
    const float4 s10 = f4add(c100, c101);  // h1 w0
    const float4 s11 = f4add(c110, c111);  // h1 w1

    float4* q = out + (size_t)b * 28311552 + i * 294912 + j * 1536 + k * 16 + c4;
    // h = 2i, w = 2j
    q[0]      = c000;
    q[8]      = f4scale(s00, 0.5f);
    q[768]    = f4scale(f4add(c000, c010), 0.5f);
    q[776]    = f4scale(f4add(s00, s01), 0.25f);
    // h = 2i+1
    q[147456] = f4scale(f4add(c000, c100), 0.5f);
    q[147464] = f4scale(f4add(s00, s10), 0.25f);
    q[148224] = f4scale(f4add(f4add(c000, c010), f4add(c100, c110)), 0.25f);
    q[148232] = f4scale(f4add(f4add(s00, s01), f4add(s10, s11)), 0.125f);
}

extern "C" void kernel_launch(void* const* d_in, const int* in_sizes, int n_in,
                              void* d_out, int out_size, void* d_ws, size_t ws_size,
                              hipStream_t stream) {
    const float4* in = (const float4*)d_in[0];
    float4* out = (float4*)d_out;
    // total threads = 2*96*96*48*8 = 7,077,888 = 27648 blocks * 256
    upsample2x_kernel<<<27648, 256, 0, stream>>>(in, out);
}